// Round 1
// baseline (16818.845 us; speedup 1.0000x reference)
//
#include <hip/hip_runtime.h>
#include <hip/hip_bf16.h>
#include <hip/hip_fp16.h>
#include <hip/hip_cooperative_groups.h>

namespace cg = cooperative_groups;

typedef __attribute__((ext_vector_type(8))) short short8;
typedef __attribute__((ext_vector_type(4))) float f32x4;

#define Hh 512
#define Bb 64
#define Ss 512
#define Gg 2048
#define NROW 32768

static __device__ inline short f2bf(float f) {
    union { float f; unsigned u; } v; v.f = f;
    unsigned r = (v.u + 0x7FFFu + ((v.u >> 16) & 1u)) >> 16;
    return (short)r;
}

static __device__ inline short8 pack_bf8(const float* p) {
    f32x4 u0 = *(const f32x4*)p;
    f32x4 u1 = *(const f32x4*)(p + 4);
    short8 t;
    t[0] = f2bf(u0[0]); t[1] = f2bf(u0[1]); t[2] = f2bf(u0[2]); t[3] = f2bf(u0[3]);
    t[4] = f2bf(u1[0]); t[5] = f2bf(u1[1]); t[6] = f2bf(u1[2]); t[7] = f2bf(u1[3]);
    return t;
}

// ---------------- prep: f32 -> bf16 for W_ih and fc_W ----------------
__global__ __launch_bounds__(256)
void prep_bf16(const float* __restrict__ wih, const float* __restrict__ fcw,
               short* __restrict__ wih_bf, short* __restrict__ fcw_bf) {
    const int n1 = Gg * 256;        // 524288
    const int n2 = 48 * Hh;         // 24576
    for (int i = blockIdx.x * blockDim.x + threadIdx.x; i < n1 + n2;
         i += gridDim.x * blockDim.x) {
        if (i < n1) wih_bf[i] = f2bf(wih[i]);
        else        fcw_bf[i - n1] = f2bf(fcw[i - n1]);
    }
}

// ---------------- px = gather(emb,x) @ W_ih^T + b_hh  (fp16 out) ----------------
__global__ __launch_bounds__(256)
void px_kernel(const int* __restrict__ x, const float* __restrict__ emb,
               const short* __restrict__ wih_bf, const float* __restrict__ bhh,
               _Float16* __restrict__ px) {
    const int w = threadIdx.x >> 6, lane = threadIdx.x & 63;
    const int lr = lane & 15, lc = lane >> 4;
    const int r0 = blockIdx.x * 64 + w * 16;

    // A-fragments: 8 k-steps of 32 (K=256), gathered embedding rows
    short8 a[8];
    const int tok = x[r0 + lr];
    const float* arow = emb + (long)tok * 256;
#pragma unroll
    for (int ks = 0; ks < 8; ks++)
        a[ks] = pack_bf8(arow + ks * 32 + lc * 8);

    for (int g0 = 0; g0 < Gg; g0 += 16) {
        f32x4 acc = {0.f, 0.f, 0.f, 0.f};
#pragma unroll
        for (int ks = 0; ks < 8; ks++) {
            short8 b = *(const short8*)(wih_bf + (g0 + lr) * 256 + ks * 32 + lc * 8);
            acc = __builtin_amdgcn_mfma_f32_16x16x32_bf16(a[ks], b, acc, 0, 0, 0);
        }
        const float bias = bhh[g0 + lr];
#pragma unroll
        for (int i = 0; i < 4; i++) {
            int r = r0 + lc * 4 + i;
            px[(long)r * Gg + g0 + lr] = (_Float16)(acc[i] + bias);
        }
    }
}

// ---------------- persistent LSTM recurrence (cooperative) ----------------
// grid = 128 WGs x 256 thr. 4 clusters x 32 WGs.
// WG: 16 batches (b0..b0+15) x 16 hidden units (J..J+15); wave w = gate group (i,f,g,o).
__global__ __launch_bounds__(256)
void lstm_kernel(const float* __restrict__ whh, const _Float16* __restrict__ px,
                 unsigned short* __restrict__ hbuf,   // [2][64][512] bf16
                 unsigned short* __restrict__ hs) {   // [32768][512] bf16
    const int wg = blockIdx.x;
    const int cl = wg >> 5;
    const int wgc = wg & 31;
    const int b0 = cl * 16, J = wgc * 16;
    const int w = threadIdx.x >> 6, lane = threadIdx.x & 63;
    const int lr = lane & 15, lc = lane >> 4;
    const int gw = w * Hh + J;   // gate-row base for this wave (i/f/g/o block)

    __shared__ float gates[4][16][16];
    __shared__ float cst[16][16];

    // W_hh B-fragments, resident in VGPRs for the whole sequence
    short8 wf[16];
#pragma unroll
    for (int ks = 0; ks < 16; ks++)
        wf[ks] = pack_bf8(whh + (long)(gw + lr) * Hh + ks * 32 + lc * 8);

    cst[threadIdx.x >> 4][threadIdx.x & 15] = 0.f;

    cg::grid_group grid = cg::this_grid();
    __syncthreads();

#pragma unroll 1
    for (int t = 0; t < Ss; t++) {
        const unsigned short* hp = hbuf + (t & 1) * (Bb * Hh);

        // A-fragments: h_{t-1} rows for this cluster's batches
        short8 af[16];
#pragma unroll
        for (int ks = 0; ks < 16; ks++)
            af[ks] = *(const short8*)(hp + (b0 + lr) * Hh + ks * 32 + lc * 8);

        // C init = precomputed input projection (+bias already folded in)
        f32x4 acc;
#pragma unroll
        for (int i = 0; i < 4; i++)
            acc[i] = (float)px[((long)(b0 + lc * 4 + i) * Ss + t) * Gg + gw + lr];

#pragma unroll
        for (int ks = 0; ks < 16; ks++)
            acc = __builtin_amdgcn_mfma_f32_16x16x32_bf16(af[ks], wf[ks], acc, 0, 0, 0);

#pragma unroll
        for (int i = 0; i < 4; i++)
            gates[w][lc * 4 + i][lr] = acc[i];
        __syncthreads();

        // elementwise cell update: 256 threads = 16 batches x 16 units
        {
            const int b = threadIdx.x >> 4, j = threadIdx.x & 15;
            const float gi = gates[0][b][j];
            const float gf = gates[1][b][j];
            const float gg = gates[2][b][j];
            const float go = gates[3][b][j];
            const float si = 1.f / (1.f + expf(-gi));
            const float sf = 1.f / (1.f + expf(-gf));
            const float tg = tanhf(gg);
            const float so = 1.f / (1.f + expf(-go));
            const float c = sf * cst[b][j] + si * tg;
            cst[b][j] = c;
            const float h = so * tanhf(c);
            const unsigned short hb = (unsigned short)f2bf(h);
            hbuf[((t + 1) & 1) * (Bb * Hh) + (b0 + b) * Hh + J + j] = hb;
            hs[((long)(b0 + b) * Ss + t) * Hh + J + j] = hb;
        }
        __threadfence();
        grid.sync();
    }
}

// ---------------- logits = hs @ fc_W^T + fc_b, then log_softmax ----------------
__global__ __launch_bounds__(256)
void fc_kernel(const unsigned short* __restrict__ hs, const short* __restrict__ fcw_bf,
               const float* __restrict__ fcb, float* __restrict__ out) {
    const int w = threadIdx.x >> 6, lane = threadIdx.x & 63;
    const int lr = lane & 15, lc = lane >> 4;
    const int r0 = blockIdx.x * 64 + w * 16;

    short8 af[16];
#pragma unroll
    for (int ks = 0; ks < 16; ks++)
        af[ks] = *(const short8*)((const short*)hs + (long)(r0 + lr) * Hh + ks * 32 + lc * 8);

    f32x4 acc[3];
#pragma unroll
    for (int nt = 0; nt < 3; nt++) {
        f32x4 a_ = {0.f, 0.f, 0.f, 0.f};
#pragma unroll
        for (int ks = 0; ks < 16; ks++) {
            short8 b = *(const short8*)(fcw_bf + (nt * 16 + lr) * Hh + ks * 32 + lc * 8);
            a_ = __builtin_amdgcn_mfma_f32_16x16x32_bf16(af[ks], b, a_, 0, 0, 0);
        }
        acc[nt] = a_;
    }

    const float bb0 = fcb[lr], bb1 = fcb[16 + lr], bb2 = fcb[32 + lr];
#pragma unroll
    for (int i = 0; i < 4; i++) {
        float v0 = acc[0][i] + bb0, v1 = acc[1][i] + bb1, v2 = acc[2][i] + bb2;
        float m = fmaxf(v0, fmaxf(v1, v2));
#pragma unroll
        for (int d = 1; d < 16; d <<= 1) m = fmaxf(m, __shfl_xor(m, d));
        float s = expf(v0 - m) + expf(v1 - m) + expf(v2 - m);
#pragma unroll
        for (int d = 1; d < 16; d <<= 1) s += __shfl_xor(s, d);
        const float lse = m + logf(s);
        const long r = r0 + lc * 4 + i;
        out[r * 48 + lr]      = v0 - lse;
        out[r * 48 + 16 + lr] = v1 - lse;
        out[r * 48 + 32 + lr] = v2 - lse;
    }
}

extern "C" void kernel_launch(void* const* d_in, const int* in_sizes, int n_in,
                              void* d_out, int out_size, void* d_ws, size_t ws_size,
                              hipStream_t stream) {
    const int*   x   = (const int*)d_in[0];
    const float* emb = (const float*)d_in[1];
    const float* wih = (const float*)d_in[2];
    const float* whh = (const float*)d_in[3];
    const float* bhh = (const float*)d_in[4];
    const float* fcw = (const float*)d_in[5];
    const float* fcb = (const float*)d_in[6];
    float* out = (float*)d_out;

    char* ws = (char*)d_ws;
    const size_t off_px   = 0;
    const size_t off_hs   = off_px + (size_t)NROW * Gg * 2;       // 134217728
    const size_t off_hbuf = off_hs + (size_t)NROW * Hh * 2;       // +33554432
    const size_t off_wih  = off_hbuf + 2 * (size_t)Bb * Hh * 2;   // +131072
    const size_t off_fcw  = off_wih + (size_t)Gg * 256 * 2;       // +1048576

    _Float16*       px     = (_Float16*)(ws + off_px);
    unsigned short* hs     = (unsigned short*)(ws + off_hs);
    unsigned short* hbuf   = (unsigned short*)(ws + off_hbuf);
    short*          wih_bf = (short*)(ws + off_wih);
    short*          fcw_bf = (short*)(ws + off_fcw);

    hipMemsetAsync(hbuf, 0, 2 * (size_t)Bb * Hh * 2, stream);
    prep_bf16<<<512, 256, 0, stream>>>(wih, fcw, wih_bf, fcw_bf);
    px_kernel<<<512, 256, 0, stream>>>(x, emb, wih_bf, bhh, px);

    void* args[] = {(void*)&whh, (void*)&px, (void*)&hbuf, (void*)&hs};
    hipLaunchCooperativeKernel((void*)lstm_kernel, dim3(128), dim3(256), args, 0, stream);

    fc_kernel<<<512, 256, 0, stream>>>(hs, fcw_bf, fcb, out);
}

// Round 2
// 4929.965 us; speedup vs baseline: 3.4116x; 3.4116x over previous
//
#include <hip/hip_runtime.h>
#include <hip/hip_bf16.h>
#include <hip/hip_fp16.h>

typedef __attribute__((ext_vector_type(8))) short short8;
typedef __attribute__((ext_vector_type(4))) float f32x4;

#define Hh 512
#define Bb 64
#define Ss 512
#define Gg 2048
#define NROW 32768

static __device__ inline short f2bf(float f) {
    union { float f; unsigned u; } v; v.f = f;
    unsigned r = (v.u + 0x7FFFu + ((v.u >> 16) & 1u)) >> 16;
    return (short)r;
}

static __device__ inline short8 pack_bf8(const float* p) {
    f32x4 u0 = *(const f32x4*)p;
    f32x4 u1 = *(const f32x4*)(p + 4);
    short8 t;
    t[0] = f2bf(u0[0]); t[1] = f2bf(u0[1]); t[2] = f2bf(u0[2]); t[3] = f2bf(u0[3]);
    t[4] = f2bf(u1[0]); t[5] = f2bf(u1[1]); t[6] = f2bf(u1[2]); t[7] = f2bf(u1[3]);
    return t;
}

// ---------------- prep: f32 -> bf16 for W_ih and fc_W ----------------
__global__ __launch_bounds__(256)
void prep_bf16(const float* __restrict__ wih, const float* __restrict__ fcw,
               short* __restrict__ wih_bf, short* __restrict__ fcw_bf) {
    const int n1 = Gg * 256;
    const int n2 = 48 * Hh;
    for (int i = blockIdx.x * blockDim.x + threadIdx.x; i < n1 + n2;
         i += gridDim.x * blockDim.x) {
        if (i < n1) wih_bf[i] = f2bf(wih[i]);
        else        fcw_bf[i - n1] = f2bf(fcw[i - n1]);
    }
}

// ---------------- px[t][b][g] = (emb[x] @ W_ih^T + b_hh)  (fp16) ----------------
__global__ __launch_bounds__(256)
void px_kernel(const int* __restrict__ x, const float* __restrict__ emb,
               const short* __restrict__ wih_bf, const float* __restrict__ bhh,
               _Float16* __restrict__ px) {
    const int w = threadIdx.x >> 6, lane = threadIdx.x & 63;
    const int lr = lane & 15, lc = lane >> 4;
    const int r0 = blockIdx.x * 64 + w * 16;

    short8 a[8];
    const int tok = x[r0 + lr];
    const float* arow = emb + (long)tok * 256;
#pragma unroll
    for (int ks = 0; ks < 8; ks++)
        a[ks] = pack_bf8(arow + ks * 32 + lc * 8);

    for (int g0 = 0; g0 < Gg; g0 += 16) {
        f32x4 acc = {0.f, 0.f, 0.f, 0.f};
#pragma unroll
        for (int ks = 0; ks < 8; ks++) {
            short8 b = *(const short8*)(wih_bf + (g0 + lr) * 256 + ks * 32 + lc * 8);
            acc = __builtin_amdgcn_mfma_f32_16x16x32_bf16(a[ks], b, acc, 0, 0, 0);
        }
        const float bias = bhh[g0 + lr];
#pragma unroll
        for (int i = 0; i < 4; i++) {
            const int r = r0 + lc * 4 + i;          // global row = b*S + s
            const int bb = r >> 9, s = r & 511;
            px[((long)s * Bb + bb) * Gg + g0 + lr] = (_Float16)(acc[i] + bias);
        }
    }
}

// ---------------- persistent LSTM recurrence ----------------
// 32 WGs x 512 thr. cluster cl = blockIdx&3 (16 batches), wgc = blockIdx>>2 (64 hidden cols).
// Wave w: gate type w&3, col half (w>>2)*32 -> 2 MFMA tiles.
// Cross-WG h exchange via agent-scope relaxed atomics (L2-bypass); per-cluster flag barrier.
__global__ __launch_bounds__(512)
void lstm_kernel(const float* __restrict__ whh, const _Float16* __restrict__ px,
                 unsigned int* __restrict__ hbuf32,   // [2][64][256] u32 = 2x bf16
                 unsigned int* __restrict__ hs32,     // [32768][256]
                 int* __restrict__ flags) {           // [4][32] (padded)
    const int cl  = blockIdx.x & 3;
    const int wgc = blockIdx.x >> 2;       // 0..7
    const int b0 = cl * 16;
    const int J0 = wgc * 64;
    const int w = threadIdx.x >> 6;        // 0..7
    const int lane = threadIdx.x & 63;
    const int lr = lane & 15, lc = lane >> 4;
    const int gt = w & 3;
    const int Jsub = (w >> 2) * 32;

    __shared__ float gates[4][16][64];     // 16 KB

    // W_hh fragments resident in VGPRs: 2 tiles x 16 k-steps
    short8 wf[2][16];
#pragma unroll
    for (int u = 0; u < 2; u++)
#pragma unroll
        for (int ks = 0; ks < 16; ks++)
            wf[u][ks] = pack_bf8(whh + (long)(gt * Hh + J0 + Jsub + u * 16 + lr) * Hh + ks * 32 + lc * 8);

    // cell state in registers: thread owns (b, j) and (b, j+1)
    const int eb = threadIdx.x >> 5;       // 0..15
    const int jp = threadIdx.x & 31;       // u32 col within WG
    float c0 = 0.f, c1 = 0.f;

    const int gr0 = gt * Hh + J0 + Jsub + lr;
    float pf[2][4];
#pragma unroll
    for (int u = 0; u < 2; u++)
#pragma unroll
        for (int i = 0; i < 4; i++)
            pf[u][i] = (float)px[((long)0 * Bb + b0 + lc * 4 + i) * Gg + gr0 + u * 16];

    int* const myflag = flags + cl * 32 + wgc;

#pragma unroll 1
    for (int t = 0; t < Ss; t++) {
        // wait for all 8 cluster WGs to have finished step t-1
        if (threadIdx.x < 8) {
            const int* fp = flags + cl * 32 + threadIdx.x;
            while (__hip_atomic_load(fp, __ATOMIC_RELAXED, __HIP_MEMORY_SCOPE_AGENT) < t)
                __builtin_amdgcn_s_sleep(1);
        }
        __syncthreads();

        // h_{t-1} fragments via coherent (L2-bypass) loads
        const unsigned long long* hb =
            (const unsigned long long*)hbuf32 + (long)(t & 1) * (Bb * Hh / 4);
        short8 af[16];
#pragma unroll
        for (int ks = 0; ks < 16; ks++) {
            union { unsigned long long q[2]; short8 s; } u_;
            unsigned long long* p0 = (unsigned long long*)hb + (b0 + lr) * 128 + ks * 8 + lc * 2;
            u_.q[0] = __hip_atomic_load(p0,     __ATOMIC_RELAXED, __HIP_MEMORY_SCOPE_AGENT);
            u_.q[1] = __hip_atomic_load(p0 + 1, __ATOMIC_RELAXED, __HIP_MEMORY_SCOPE_AGENT);
            af[ks] = u_.s;
        }

        f32x4 acc[2];
#pragma unroll
        for (int u = 0; u < 2; u++) {
            acc[u][0] = pf[u][0]; acc[u][1] = pf[u][1];
            acc[u][2] = pf[u][2]; acc[u][3] = pf[u][3];
        }
#pragma unroll
        for (int ks = 0; ks < 16; ks++) {
            acc[0] = __builtin_amdgcn_mfma_f32_16x16x32_bf16(af[ks], wf[0][ks], acc[0], 0, 0, 0);
            acc[1] = __builtin_amdgcn_mfma_f32_16x16x32_bf16(af[ks], wf[1][ks], acc[1], 0, 0, 0);
        }

#pragma unroll
        for (int u = 0; u < 2; u++)
#pragma unroll
            for (int i = 0; i < 4; i++)
                gates[gt][lc * 4 + i][Jsub + u * 16 + lr] = acc[u][i];
        __syncthreads();

        // elementwise cell update: thread -> (eb, 2*jp), (eb, 2*jp+1)
        {
            const int j = jp * 2;
            const float gi0 = gates[0][eb][j],   gi1 = gates[0][eb][j + 1];
            const float gf0 = gates[1][eb][j],   gf1 = gates[1][eb][j + 1];
            const float gg0 = gates[2][eb][j],   gg1 = gates[2][eb][j + 1];
            const float go0 = gates[3][eb][j],   go1 = gates[3][eb][j + 1];
            const float si0 = 1.f / (1.f + expf(-gi0)), si1 = 1.f / (1.f + expf(-gi1));
            const float sf0 = 1.f / (1.f + expf(-gf0)), sf1 = 1.f / (1.f + expf(-gf1));
            const float tg0 = tanhf(gg0),               tg1 = tanhf(gg1);
            const float so0 = 1.f / (1.f + expf(-go0)), so1 = 1.f / (1.f + expf(-go1));
            c0 = sf0 * c0 + si0 * tg0;
            c1 = sf1 * c1 + si1 * tg1;
            const float h0 = so0 * tanhf(c0);
            const float h1 = so1 * tanhf(c1);
            const unsigned hpack = (unsigned)(unsigned short)f2bf(h0)
                                 | ((unsigned)(unsigned short)f2bf(h1) << 16);
            unsigned int* hw = hbuf32 + (long)((t + 1) & 1) * (Bb * Hh / 2)
                               + (b0 + eb) * 256 + (J0 >> 1) + jp;
            __hip_atomic_store(hw, hpack, __ATOMIC_RELAXED, __HIP_MEMORY_SCOPE_AGENT);
            hs32[((long)(b0 + eb) * Ss + t) * 256 + (J0 >> 1) + jp] = hpack;
        }
        // __syncthreads drains each wave's vmcnt(0) -> h stores globally visible
        __syncthreads();
        if (threadIdx.x == 0)
            __hip_atomic_store(myflag, t + 1, __ATOMIC_RELAXED, __HIP_MEMORY_SCOPE_AGENT);

        // prefetch px for next step; force issue+complete before the spin
        const int tn = (t + 1 < Ss) ? t + 1 : t;
#pragma unroll
        for (int u = 0; u < 2; u++)
#pragma unroll
            for (int i = 0; i < 4; i++)
                pf[u][i] = (float)px[((long)tn * Bb + b0 + lc * 4 + i) * Gg + gr0 + u * 16];
        asm volatile("" : "+v"(pf[0][0]), "+v"(pf[0][1]), "+v"(pf[0][2]), "+v"(pf[0][3]),
                          "+v"(pf[1][0]), "+v"(pf[1][1]), "+v"(pf[1][2]), "+v"(pf[1][3]));
    }
}

// ---------------- logits = hs @ fc_W^T + fc_b, then log_softmax ----------------
__global__ __launch_bounds__(256)
void fc_kernel(const unsigned short* __restrict__ hs, const short* __restrict__ fcw_bf,
               const float* __restrict__ fcb, float* __restrict__ out) {
    const int w = threadIdx.x >> 6, lane = threadIdx.x & 63;
    const int lr = lane & 15, lc = lane >> 4;
    const int r0 = blockIdx.x * 64 + w * 16;

    short8 af[16];
#pragma unroll
    for (int ks = 0; ks < 16; ks++)
        af[ks] = *(const short8*)((const short*)hs + (long)(r0 + lr) * Hh + ks * 32 + lc * 8);

    f32x4 acc[3];
#pragma unroll
    for (int nt = 0; nt < 3; nt++) {
        f32x4 a_ = {0.f, 0.f, 0.f, 0.f};
#pragma unroll
        for (int ks = 0; ks < 16; ks++) {
            short8 b = *(const short8*)(fcw_bf + (nt * 16 + lr) * Hh + ks * 32 + lc * 8);
            a_ = __builtin_amdgcn_mfma_f32_16x16x32_bf16(af[ks], b, a_, 0, 0, 0);
        }
        acc[nt] = a_;
    }

    const float bb0 = fcb[lr], bb1 = fcb[16 + lr], bb2 = fcb[32 + lr];
#pragma unroll
    for (int i = 0; i < 4; i++) {
        float v0 = acc[0][i] + bb0, v1 = acc[1][i] + bb1, v2 = acc[2][i] + bb2;
        float m = fmaxf(v0, fmaxf(v1, v2));
#pragma unroll
        for (int d = 1; d < 16; d <<= 1) m = fmaxf(m, __shfl_xor(m, d));
        float s = expf(v0 - m) + expf(v1 - m) + expf(v2 - m);
#pragma unroll
        for (int d = 1; d < 16; d <<= 1) s += __shfl_xor(s, d);
        const float lse = m + logf(s);
        const long r = r0 + lc * 4 + i;
        out[r * 48 + lr]      = v0 - lse;
        out[r * 48 + 16 + lr] = v1 - lse;
        out[r * 48 + 32 + lr] = v2 - lse;
    }
}

extern "C" void kernel_launch(void* const* d_in, const int* in_sizes, int n_in,
                              void* d_out, int out_size, void* d_ws, size_t ws_size,
                              hipStream_t stream) {
    const int*   x   = (const int*)d_in[0];
    const float* emb = (const float*)d_in[1];
    const float* wih = (const float*)d_in[2];
    const float* whh = (const float*)d_in[3];
    const float* bhh = (const float*)d_in[4];
    const float* fcw = (const float*)d_in[5];
    const float* fcb = (const float*)d_in[6];
    float* out = (float*)d_out;

    char* ws = (char*)d_ws;
    const size_t off_px    = 0;
    const size_t off_hs    = off_px + (size_t)NROW * Gg * 2;        // 134217728
    const size_t off_hbuf  = off_hs + (size_t)NROW * Hh * 2;        // +33554432
    const size_t off_flags = off_hbuf + 2 * (size_t)Bb * Hh * 2;    // +131072
    const size_t off_wih   = off_flags + 512;
    const size_t off_fcw   = off_wih + (size_t)Gg * 256 * 2;

    _Float16*     px     = (_Float16*)(ws + off_px);
    unsigned int* hs32   = (unsigned int*)(ws + off_hs);
    unsigned int* hbuf32 = (unsigned int*)(ws + off_hbuf);
    int*          flags  = (int*)(ws + off_flags);
    short*        wih_bf = (short*)(ws + off_wih);
    short*        fcw_bf = (short*)(ws + off_fcw);

    hipMemsetAsync(ws + off_hbuf, 0, 2 * (size_t)Bb * Hh * 2 + 512, stream);
    prep_bf16<<<512, 256, 0, stream>>>(wih, fcw, wih_bf, fcw_bf);
    px_kernel<<<512, 256, 0, stream>>>(x, emb, wih_bf, bhh, px);

    void* args[] = {(void*)&whh, (void*)&px, (void*)&hbuf32, (void*)&hs32, (void*)&flags};
    hipLaunchCooperativeKernel((void*)lstm_kernel, dim3(32), dim3(512), args, 0, stream);

    fc_kernel<<<512, 256, 0, stream>>>((const unsigned short*)hs32, fcw_bf, fcb, out);
}

// Round 3
// 1518.669 us; speedup vs baseline: 11.0747x; 3.2462x over previous
//
#include <hip/hip_runtime.h>
#include <hip/hip_bf16.h>
#include <hip/hip_fp16.h>

typedef __attribute__((ext_vector_type(8))) short short8;
typedef __attribute__((ext_vector_type(4))) float f32x4;
typedef __attribute__((ext_vector_type(2))) unsigned long long ull2;

#define Hh 512
#define Bb 64
#define Ss 512
#define Gg 2048
#define NROW 32768

static __device__ inline short f2bf(float f) {
    union { float f; unsigned u; } v; v.f = f;
    unsigned r = (v.u + 0x7FFFu + ((v.u >> 16) & 1u)) >> 16;
    return (short)r;
}

static __device__ inline short8 pack_bf8(const float* p) {
    f32x4 u0 = *(const f32x4*)p;
    f32x4 u1 = *(const f32x4*)(p + 4);
    short8 t;
    t[0] = f2bf(u0[0]); t[1] = f2bf(u0[1]); t[2] = f2bf(u0[2]); t[3] = f2bf(u0[3]);
    t[4] = f2bf(u1[0]); t[5] = f2bf(u1[1]); t[6] = f2bf(u1[2]); t[7] = f2bf(u1[3]);
    return t;
}

static __device__ inline float fsigmoid(float x) {
    // 1/(1+2^(-x*log2e)); limits handled: exp2(+inf)->inf->rcp->0 correct
    return __builtin_amdgcn_rcpf(1.f + __builtin_amdgcn_exp2f(x * -1.44269504088896f));
}
static __device__ inline float ftanh(float x) {
    float xc = fminf(fmaxf(x, -15.f), 15.f);
    float e = __builtin_amdgcn_exp2f(xc * 2.88539008177793f); // e^(2x)
    return (e - 1.f) / (e + 1.f);
}

// ---------------- prep: f32 -> bf16 for W_ih and fc_W ----------------
__global__ __launch_bounds__(256)
void prep_bf16(const float* __restrict__ wih, const float* __restrict__ fcw,
               short* __restrict__ wih_bf, short* __restrict__ fcw_bf) {
    const int n1 = Gg * 256;
    const int n2 = 48 * Hh;
    for (int i = blockIdx.x * blockDim.x + threadIdx.x; i < n1 + n2;
         i += gridDim.x * blockDim.x) {
        if (i < n1) wih_bf[i] = f2bf(wih[i]);
        else        fcw_bf[i - n1] = f2bf(fcw[i - n1]);
    }
}

// ---------------- px[t][b][g] = (emb[x] @ W_ih^T + b_hh)  (fp16) ----------------
__global__ __launch_bounds__(256)
void px_kernel(const int* __restrict__ x, const float* __restrict__ emb,
               const short* __restrict__ wih_bf, const float* __restrict__ bhh,
               _Float16* __restrict__ px) {
    const int w = threadIdx.x >> 6, lane = threadIdx.x & 63;
    const int lr = lane & 15, lc = lane >> 4;
    const int r0 = blockIdx.x * 64 + w * 16;

    short8 a[8];
    const int tok = x[r0 + lr];
    const float* arow = emb + (long)tok * 256;
#pragma unroll
    for (int ks = 0; ks < 8; ks++)
        a[ks] = pack_bf8(arow + ks * 32 + lc * 8);

    for (int g0 = 0; g0 < Gg; g0 += 16) {
        f32x4 acc = {0.f, 0.f, 0.f, 0.f};
#pragma unroll
        for (int ks = 0; ks < 8; ks++) {
            short8 b = *(const short8*)(wih_bf + (g0 + lr) * 256 + ks * 32 + lc * 8);
            acc = __builtin_amdgcn_mfma_f32_16x16x32_bf16(a[ks], b, acc, 0, 0, 0);
        }
        const float bias = bhh[g0 + lr];
#pragma unroll
        for (int i = 0; i < 4; i++) {
            const int r = r0 + lc * 4 + i;          // global row = b*S + s
            const int bb = r >> 9, s = r & 511;
            px[((long)s * Bb + bb) * Gg + g0 + lr] = (_Float16)(acc[i] + bias);
        }
    }
}

// ---------------- persistent LSTM recurrence ----------------
// 32 WGs x 512 thr. cluster cl = blockIdx&3 (16 batches), wgc = blockIdx>>2 (64 hidden cols).
// h exchange: sc stores -> flag; readers coop-load 16KB once per WG into swizzled LDS.
__global__ __launch_bounds__(512)
void lstm_kernel(const float* __restrict__ whh, const _Float16* __restrict__ px,
                 unsigned int* __restrict__ hbuf32,   // [2][64][256] u32 = 2x bf16
                 unsigned int* __restrict__ hs32,     // [32768][256]
                 int* __restrict__ flags) {           // [4][32] (padded)
    const int cl  = blockIdx.x & 3;
    const int wgc = blockIdx.x >> 2;       // 0..7
    const int b0 = cl * 16;
    const int J0 = wgc * 64;
    const int w = threadIdx.x >> 6;        // 0..7
    const int lane = threadIdx.x & 63;
    const int lr = lane & 15, lc = lane >> 4;
    const int gt = w & 3;
    const int Jsub = (w >> 2) * 32;

    __shared__ float gates[4][16][64];                     // 16 KB
    __shared__ __align__(16) unsigned int hlds[16 * 256];  // 16 KB, swizzled

    // W_hh fragments resident in VGPRs: 2 tiles x 16 k-steps
    short8 wf[2][16];
#pragma unroll
    for (int u = 0; u < 2; u++)
#pragma unroll
        for (int ks = 0; ks < 16; ks++)
            wf[u][ks] = pack_bf8(whh + (long)(gt * Hh + J0 + Jsub + u * 16 + lr) * Hh + ks * 32 + lc * 8);

    // cell state in registers: thread owns (eb, 2*jp), (eb, 2*jp+1)
    const int eb = threadIdx.x >> 5;       // 0..15
    const int jp = threadIdx.x & 31;
    float c0 = 0.f, c1 = 0.f;

    const int gr0 = gt * Hh + J0 + Jsub + lr;
    float pf[2][4];
#pragma unroll
    for (int u = 0; u < 2; u++)
#pragma unroll
        for (int i = 0; i < 4; i++)
            pf[u][i] = (float)px[((long)0 * Bb + b0 + lc * 4 + i) * Gg + gr0 + u * 16];

    int* const myflag = flags + cl * 32 + wgc;

#pragma unroll 1
    for (int t = 0; t < Ss; t++) {
        // wait for all 8 cluster WGs to have finished step t-1
        if (threadIdx.x < 8) {
            const int* fp = flags + cl * 32 + threadIdx.x;
            while (__hip_atomic_load(fp, __ATOMIC_RELAXED, __HIP_MEMORY_SCOPE_AGENT) < t)
                __builtin_amdgcn_s_sleep(1);
        }
        __syncthreads();   // sync0: also drains last iter's px prefetch + hs store

        // coop-load cluster h tile (16 rows x 512 bf16 = 16KB) into swizzled LDS
        {
            const unsigned long long* hb =
                (const unsigned long long*)hbuf32 + (long)(t & 1) * (Bb * Hh / 4);
            int m = threadIdx.x;
#pragma unroll
            for (int k = 0; k < 2; k++, m += 512) {
                const int row = m >> 6;            // 0..15
                const int c   = (m & 63) * 4;      // u32 col, 16B chunk
                const unsigned long long* p = hb + (long)(b0 + row) * 128 + (c >> 1);
                unsigned long long q0 = __hip_atomic_load(p,     __ATOMIC_RELAXED, __HIP_MEMORY_SCOPE_AGENT);
                unsigned long long q1 = __hip_atomic_load(p + 1, __ATOMIC_RELAXED, __HIP_MEMORY_SCOPE_AGENT);
                const int sw = c ^ ((row & 7) << 2);
                ull2 q; q[0] = q0; q[1] = q1;
                *(ull2*)&hlds[row * 256 + sw] = q;
            }
        }
        __syncthreads();   // syncA: h tile ready in LDS

        f32x4 acc[2];
#pragma unroll
        for (int u = 0; u < 2; u++) {
            acc[u][0] = pf[u][0]; acc[u][1] = pf[u][1];
            acc[u][2] = pf[u][2]; acc[u][3] = pf[u][3];
        }

#pragma unroll
        for (int ks = 0; ks < 16; ks++) {
            const int c = ks * 16 + lc * 4;
            const short8 af = *(const short8*)&hlds[lr * 256 + (c ^ ((lr & 7) << 2))];
            acc[0] = __builtin_amdgcn_mfma_f32_16x16x32_bf16(af, wf[0][ks], acc[0], 0, 0, 0);
            acc[1] = __builtin_amdgcn_mfma_f32_16x16x32_bf16(af, wf[1][ks], acc[1], 0, 0, 0);
        }

#pragma unroll
        for (int u = 0; u < 2; u++)
#pragma unroll
            for (int i = 0; i < 4; i++)
                gates[gt][lc * 4 + i][Jsub + u * 16 + lr] = acc[u][i];
        __syncthreads();   // syncB: gates ready

        // elementwise cell update
        unsigned hpack;
        {
            const int j = jp * 2;
            const float gi0 = gates[0][eb][j],   gi1 = gates[0][eb][j + 1];
            const float gf0 = gates[1][eb][j],   gf1 = gates[1][eb][j + 1];
            const float gg0 = gates[2][eb][j],   gg1 = gates[2][eb][j + 1];
            const float go0 = gates[3][eb][j],   go1 = gates[3][eb][j + 1];
            c0 = fsigmoid(gf0) * c0 + fsigmoid(gi0) * ftanh(gg0);
            c1 = fsigmoid(gf1) * c1 + fsigmoid(gi1) * ftanh(gg1);
            const float h0 = fsigmoid(go0) * ftanh(c0);
            const float h1 = fsigmoid(go1) * ftanh(c1);
            hpack = (unsigned)(unsigned short)f2bf(h0)
                  | ((unsigned)(unsigned short)f2bf(h1) << 16);
            unsigned int* hw = hbuf32 + (long)((t + 1) & 1) * (Bb * Hh / 2)
                               + (b0 + eb) * 256 + (J0 >> 1) + jp;
            __hip_atomic_store(hw, hpack, __ATOMIC_RELAXED, __HIP_MEMORY_SCOPE_AGENT);
        }
        __syncthreads();   // syncC: drains all waves' h stores (vmcnt0 before barrier)
        if (threadIdx.x == 0)
            __hip_atomic_store(myflag, t + 1, __ATOMIC_RELAXED, __HIP_MEMORY_SCOPE_AGENT);

        // off the critical path: px prefetch for t+1 and hs history store;
        // both drain during the next poll/sync0.
        const int tn = (t + 1 < Ss) ? t + 1 : t;
#pragma unroll
        for (int u = 0; u < 2; u++)
#pragma unroll
            for (int i = 0; i < 4; i++)
                pf[u][i] = (float)px[((long)tn * Bb + b0 + lc * 4 + i) * Gg + gr0 + u * 16];
        hs32[((long)(b0 + eb) * Ss + t) * 256 + (J0 >> 1) + jp] = hpack;
    }
}

// ---------------- logits = hs @ fc_W^T + fc_b, then log_softmax ----------------
__global__ __launch_bounds__(256)
void fc_kernel(const unsigned short* __restrict__ hs, const short* __restrict__ fcw_bf,
               const float* __restrict__ fcb, float* __restrict__ out) {
    const int w = threadIdx.x >> 6, lane = threadIdx.x & 63;
    const int lr = lane & 15, lc = lane >> 4;
    const int r0 = blockIdx.x * 64 + w * 16;

    short8 af[16];
#pragma unroll
    for (int ks = 0; ks < 16; ks++)
        af[ks] = *(const short8*)((const short*)hs + (long)(r0 + lr) * Hh + ks * 32 + lc * 8);

    f32x4 acc[3];
#pragma unroll
    for (int nt = 0; nt < 3; nt++) {
        f32x4 a_ = {0.f, 0.f, 0.f, 0.f};
#pragma unroll
        for (int ks = 0; ks < 16; ks++) {
            short8 b = *(const short8*)(fcw_bf + (nt * 16 + lr) * Hh + ks * 32 + lc * 8);
            a_ = __builtin_amdgcn_mfma_f32_16x16x32_bf16(af[ks], b, a_, 0, 0, 0);
        }
        acc[nt] = a_;
    }

    const float bb0 = fcb[lr], bb1 = fcb[16 + lr], bb2 = fcb[32 + lr];
#pragma unroll
    for (int i = 0; i < 4; i++) {
        float v0 = acc[0][i] + bb0, v1 = acc[1][i] + bb1, v2 = acc[2][i] + bb2;
        float m = fmaxf(v0, fmaxf(v1, v2));
#pragma unroll
        for (int d = 1; d < 16; d <<= 1) m = fmaxf(m, __shfl_xor(m, d));
        float s = expf(v0 - m) + expf(v1 - m) + expf(v2 - m);
#pragma unroll
        for (int d = 1; d < 16; d <<= 1) s += __shfl_xor(s, d);
        const float lse = m + logf(s);
        const long r = r0 + lc * 4 + i;
        out[r * 48 + lr]      = v0 - lse;
        out[r * 48 + 16 + lr] = v1 - lse;
        out[r * 48 + 32 + lr] = v2 - lse;
    }
}

extern "C" void kernel_launch(void* const* d_in, const int* in_sizes, int n_in,
                              void* d_out, int out_size, void* d_ws, size_t ws_size,
                              hipStream_t stream) {
    const int*   x   = (const int*)d_in[0];
    const float* emb = (const float*)d_in[1];
    const float* wih = (const float*)d_in[2];
    const float* whh = (const float*)d_in[3];
    const float* bhh = (const float*)d_in[4];
    const float* fcw = (const float*)d_in[5];
    const float* fcb = (const float*)d_in[6];
    float* out = (float*)d_out;

    char* ws = (char*)d_ws;
    const size_t off_px    = 0;
    const size_t off_hs    = off_px + (size_t)NROW * Gg * 2;        // 134217728
    const size_t off_hbuf  = off_hs + (size_t)NROW * Hh * 2;        // +33554432
    const size_t off_flags = off_hbuf + 2 * (size_t)Bb * Hh * 2;    // +131072
    const size_t off_wih   = off_flags + 512;
    const size_t off_fcw   = off_wih + (size_t)Gg * 256 * 2;

    _Float16*     px     = (_Float16*)(ws + off_px);
    unsigned int* hs32   = (unsigned int*)(ws + off_hs);
    unsigned int* hbuf32 = (unsigned int*)(ws + off_hbuf);
    int*          flags  = (int*)(ws + off_flags);
    short*        wih_bf = (short*)(ws + off_wih);
    short*        fcw_bf = (short*)(ws + off_fcw);

    hipMemsetAsync(ws + off_hbuf, 0, 2 * (size_t)Bb * Hh * 2 + 512, stream);
    prep_bf16<<<512, 256, 0, stream>>>(wih, fcw, wih_bf, fcw_bf);
    px_kernel<<<512, 256, 0, stream>>>(x, emb, wih_bf, bhh, px);

    void* args[] = {(void*)&whh, (void*)&px, (void*)&hbuf32, (void*)&hs32, (void*)&flags};
    hipLaunchCooperativeKernel((void*)lstm_kernel, dim3(32), dim3(512), args, 0, stream);

    fc_kernel<<<512, 256, 0, stream>>>((const unsigned short*)hs32, fcw_bf, fcb, out);
}